// Round 9
// baseline (86.054 us; speedup 1.0000x reference)
//
#include <hip/hip_runtime.h>
#include <hip/hip_bf16.h>
#include <stdint.h>

// Recommender: B=4096 users, L=200 history, D=64 emb, F=100000 films.
// Kernel A (stats): ONE USER PER WAVE, lane = dim. 4 independent waves per
//   256-thread block, zero barriers. Per wave: stage {h<<8, rat+0.1-mean} pairs
//   in a private LDS slice; gather loop runs exactly n rows, each row one
//   fully-coalesced 256B load + broadcast ds_read_b64; min/max/sum lane-local;
//   16-bit sortable keys packed 2/word, per-32-key chunk dual 16x16
//   bit-transpose into 112 plane registers; bit-serial popc median select with
//   ZERO cross-lane ops. L2-normalize via 6 shfl_xor; write x=[ue,fe] (Bx320).
// Kernel B: tiny MLP 320->128->64->1 + sigmoid, 4 users/block (round-3 code).

#define B_ 4096
#define L_ 200
#define D_ 64

__global__ __launch_bounds__(256, 3) void stats_kernel(
    const int* __restrict__ film_hist,
    const float* __restrict__ ratings,
    const int* __restrict__ lengths,
    const int* __restrict__ film_indices,
    const float* __restrict__ emb,
    float* __restrict__ x)
{
  __shared__ uint2 pair_s[4][L_];            // per-wave slice: {h<<8, wgt bits}

  const int t = threadIdx.x;
  const int wv = t >> 6;
  const int lane = t & 63;
  const int b = blockIdx.x * 4 + wv;
  const int n = lengths[b];                  // wave-uniform

  // film embedding (issue early; fully coalesced)
  const int fi = film_indices[b];
  const float fev = emb[(size_t)fi * D_ + lane];

  // ---- stage history+ratings into this wave's LDS slice (no barrier:
  //      wave-local writes, compiler inserts lgkmcnt waits) ----
  const int*   hp = film_hist + (size_t)b * L_;
  const float* rp = ratings  + (size_t)b * L_;
  int hv[4]; float rv[4]; float rsum = 0.f;
  #pragma unroll
  for (int j = 0; j < 4; ++j) {
    const int l = lane + 64*j;
    const bool v = l < n;
    hv[j] = v ? hp[l] : 0;
    rv[j] = v ? rp[l] : 0.f;
    rsum += v ? rv[j] : 0.f;
  }
  #pragma unroll
  for (int off = 32; off; off >>= 1) rsum += __shfl_xor(rsum, off);
  const float mr1 = 0.1f - rsum / (float)n;

  uint2* ps = pair_s[wv];
  #pragma unroll
  for (int j = 0; j < 4; ++j) {
    const int l = lane + 64*j;
    if (l < n) {
      uint2 e; e.x = ((uint32_t)hv[j]) << 8;           // byte offset into emb
      e.y = __float_as_uint(rv[j] + mr1);
      ps[l] = e;
    }
  }

  // ---- gather + stats + bit-plane build: rows 0..n-1, 7 chunks of 32 ----
  float vmin = __builtin_inff(), vmax = -__builtin_inff(), vsum = 0.f;
  uint32_t PL[7][16];
  const char* eb = (const char*)emb;
  const uint32_t lane4 = (uint32_t)lane * 4u;

  #pragma unroll
  for (int c = 0; c < 7; ++c) {
    if (n > 32*c) {                          // wave-uniform guard
      uint32_t W[16];
      #pragma unroll
      for (int p = 0; p < 16; ++p) {
        const int i0 = 32*c + 2*p, i1 = i0 + 1;
        const int l0 = (i0 < n) ? i0 : (n-1);
        const int l1 = (i1 < n) ? i1 : (n-1);
        const uint2 e0 = ps[l0];
        const uint2 e1 = ps[l1];
        const float w0 = *(const float*)(eb + (e0.x + lane4)) * __uint_as_float(e0.y);
        const float w1 = *(const float*)(eb + (e1.x + lane4)) * __uint_as_float(e1.y);
        vmin = fminf(vmin, fminf(w0, w1));
        vmax = fmaxf(vmax, fmaxf(w0, w1));
        vsum += (i0 < n) ? w0 : 0.f;         // clamped dups masked out of sum
        vsum += (i1 < n) ? w1 : 0.f;
        const uint32_t u0 = __float_as_uint(w0);
        const uint32_t u1 = __float_as_uint(w1);
        const uint32_t k0 = u0 ^ (0x80000000u | (uint32_t)((int32_t)u0 >> 31));
        const uint32_t k1 = u1 ^ (0x80000000u | (uint32_t)((int32_t)u1 >> 31));
        W[p] = (k0 >> 16) | (k1 & 0xFFFF0000u);        // keys i0,i1 packed
      }
      // dual 16x16 bit-matrix transpose (verified): plane for key-bit bb is
      // W[15-bb]; key i sits at plane bit (15-(i>>1)) + 16*(i&1).
      #define XS(k, jj, m) { uint32_t tt = ((W[k] ^ (W[(k)|(jj)] >> (jj))) & (m)); \
                             W[k] ^= tt; W[(k)|(jj)] ^= (tt << (jj)); }
      XS(0,8,0x00FF00FFu) XS(1,8,0x00FF00FFu) XS(2,8,0x00FF00FFu) XS(3,8,0x00FF00FFu)
      XS(4,8,0x00FF00FFu) XS(5,8,0x00FF00FFu) XS(6,8,0x00FF00FFu) XS(7,8,0x00FF00FFu)
      XS(0,4,0x0F0F0F0Fu) XS(1,4,0x0F0F0F0Fu) XS(2,4,0x0F0F0F0Fu) XS(3,4,0x0F0F0F0Fu)
      XS(8,4,0x0F0F0F0Fu) XS(9,4,0x0F0F0F0Fu) XS(10,4,0x0F0F0F0Fu) XS(11,4,0x0F0F0F0Fu)
      XS(0,2,0x33333333u) XS(1,2,0x33333333u) XS(4,2,0x33333333u) XS(5,2,0x33333333u)
      XS(8,2,0x33333333u) XS(9,2,0x33333333u) XS(12,2,0x33333333u) XS(13,2,0x33333333u)
      XS(0,1,0x55555555u) XS(2,1,0x55555555u) XS(4,1,0x55555555u) XS(6,1,0x55555555u)
      XS(8,1,0x55555555u) XS(10,1,0x55555555u) XS(12,1,0x55555555u) XS(14,1,0x55555555u)
      #undef XS
      #pragma unroll
      for (int j = 0; j < 16; ++j) PL[c][j] = W[j];
    } else {
      #pragma unroll
      for (int j = 0; j < 16; ++j) PL[c][j] = 0u;
    }
  }

  // ---- alive masks (same formula as verified rounds, per chunk) ----
  uint32_t alive[7];
  #pragma unroll
  for (int c = 0; c < 7; ++c) {
    int v = n - 32*c; v = (v < 0) ? 0 : (v > 32 ? 32 : v);
    const int ce = (v + 1) >> 1, cf = v >> 1;
    uint32_t a = ((1u << ce) - 1u) << (16 - ce);
    if (cf) a |= ((1u << cf) - 1u) << (32 - cf);
    alive[c] = a;
  }

  // ---- bit-serial select of k-th smallest key: zero cross-lane ops ----
  int k = (n - 1) >> 1;
  int na = n;
  uint32_t prefix = 0;
  #pragma unroll
  for (int bb = 15; bb >= 0; --bb) {
    uint32_t t1[7];
    int cnt1 = 0;
    #pragma unroll
    for (int c = 0; c < 7; ++c) {
      t1[c] = alive[c] & PL[c][15 - bb];
      cnt1 += __popc(t1[c]);
    }
    const int cnt0 = na - cnt1;
    const bool zs = (k < cnt0);
    #pragma unroll
    for (int c = 0; c < 7; ++c)
      alive[c] = zs ? (alive[c] ^ t1[c]) : t1[c];
    na = zs ? cnt0 : cnt1;
    k  = zs ? k : (k - cnt0);
    prefix = zs ? prefix : (prefix | (1u << bb));
  }

  uint32_t key32 = (prefix << 16) | 0x8000u;           // bucket midpoint
  const float med = (prefix & 0x8000u) ? __uint_as_float(key32 ^ 0x80000000u)
                                       : __uint_as_float(~key32);
  const float mean = vsum / (float)n;

  // ---- L2-normalize (wave reduce of 4-term sumsq) and write x ----
  float ss = vmin*vmin + vmax*vmax + mean*mean + med*med;
  #pragma unroll
  for (int off = 32; off; off >>= 1) ss += __shfl_xor(ss, off);
  const float rn = 1.0f / sqrtf(ss);

  float* xb = x + (size_t)b * 320;
  xb[lane]        = vmin * rn;
  xb[64  + lane]  = vmax * rn;
  xb[128 + lane]  = mean * rn;
  xb[192 + lane]  = med  * rn;
  xb[256 + lane]  = fev;
}

#define U_ 4   // users per MLP block -> 1024 blocks

__global__ __launch_bounds__(256) void mlp_kernel(
    const float* __restrict__ x,
    const float* __restrict__ W1, const float* __restrict__ b1,
    const float* __restrict__ W2, const float* __restrict__ b2,
    const float* __restrict__ W3, const float* __restrict__ b3,
    float* __restrict__ out)
{
  __shared__ float xs[U_*320];
  __shared__ float h1s[U_*128];
  __shared__ float h2s[U_*64];
  const int t = threadIdx.x;
  const int u0 = blockIdx.x * U_;

  for (int i = t; i < U_*80; i += 256)
    ((float4*)xs)[i] = ((const float4*)(x + (size_t)u0*320))[i];
  __syncthreads();

  // h1 = relu(x @ W1 + b1): 4 users x 128 out; thread = (j, 2-user group)
  {
    const int j = t & 127, g = t >> 7;
    const int ub = g*2;
    float acc[2];
    const float bj = b1[j];
    acc[0] = bj; acc[1] = bj;
    for (int i = 0; i < 320; i += 4) {
      float w0 = W1[(i+0)*128 + j];
      float w1 = W1[(i+1)*128 + j];
      float w2 = W1[(i+2)*128 + j];
      float w3 = W1[(i+3)*128 + j];
      #pragma unroll
      for (int q = 0; q < 2; ++q) {
        float4 xv = *(const float4*)&xs[(ub+q)*320 + i];   // LDS broadcast in-wave
        acc[q] += xv.x*w0 + xv.y*w1 + xv.z*w2 + xv.w*w3;
      }
    }
    #pragma unroll
    for (int q = 0; q < 2; ++q) h1s[(ub+q)*128 + j] = fmaxf(acc[q], 0.f);
  }
  __syncthreads();

  // h2 = relu(h1 @ W2 + b2): 4 users x 64 out, 1 user per 64-thread group
  {
    const int j = t & 63, g = t >> 6;
    float acc = b2[j];
    for (int i = 0; i < 128; i += 4) {
      float w0 = W2[(i+0)*64 + j];
      float w1 = W2[(i+1)*64 + j];
      float w2 = W2[(i+2)*64 + j];
      float w3 = W2[(i+3)*64 + j];
      float4 hv = *(const float4*)&h1s[g*128 + i];
      acc += hv.x*w0 + hv.y*w1 + hv.z*w2 + hv.w*w3;
    }
    h2s[g*64 + j] = fmaxf(acc, 0.f);
  }
  __syncthreads();

  // out = sigmoid(h2 @ W3 + b3)
  if (t < U_*4) {
    const int u = t >> 2, sub = t & 3;
    float a = 0.f;
    #pragma unroll
    for (int i = 0; i < 16; ++i) a += h2s[u*64 + sub*16 + i] * W3[sub*16 + i];
    a += __shfl_xor(a, 1);
    a += __shfl_xor(a, 2);
    if (sub == 0) out[u0 + u] = 1.f / (1.f + __expf(-(a + b3[0])));
  }
}

extern "C" void kernel_launch(void* const* d_in, const int* in_sizes, int n_in,
                              void* d_out, int out_size, void* d_ws, size_t ws_size,
                              hipStream_t stream) {
  const int*   film_hist = (const int*)d_in[0];
  const float* ratings   = (const float*)d_in[1];
  const int*   lengths   = (const int*)d_in[2];
  const int*   film_idx  = (const int*)d_in[3];
  const float* emb       = (const float*)d_in[4];
  const float* W1 = (const float*)d_in[5];
  const float* b1 = (const float*)d_in[6];
  const float* W2 = (const float*)d_in[7];
  const float* b2 = (const float*)d_in[8];
  const float* W3 = (const float*)d_in[9];
  const float* b3 = (const float*)d_in[10];

  float* xbuf = (float*)d_ws;                 // B*320 f32 = 5.24 MB
  float* outp = (float*)d_out;

  stats_kernel<<<B_/4, 256, 0, stream>>>(film_hist, ratings, lengths, film_idx, emb, xbuf);
  mlp_kernel<<<B_/U_, 256, 0, stream>>>(xbuf, W1, b1, W2, b2, W3, b3, outp);
}

// Round 10
// 58.274 us; speedup vs baseline: 1.4767x; 1.4767x over previous
//
#include <hip/hip_runtime.h>
#include <hip/hip_bf16.h>
#include <stdint.h>

// Recommender: B=4096 users, L=200 history, D=64 emb, F=100000 films.
// Kernel A (stats): ONE USER PER WAVE, ONE WAVE PER BLOCK (64 threads,
//   4096 blocks), lane = dim. Zero barriers, zero inter-wave coupling.
//   Per wave: stage {h<<8, rat+0.1-mean} pairs in private LDS; gather loop
//   one coalesced 256B row per history entry; min/max/sum lane-local; 16-bit
//   sortable keys packed 2/word, per-32-key-chunk dual 16x16 bit-transpose
//   into 112 plane VGPRs (NO occupancy clamp -> no spill); bit-serial popc
//   median select with zero cross-lane ops. L2-normalize via shfl; write
//   x=[ue,fe] (Bx320) to workspace.
// Kernel B: tiny MLP 320->128->64->1 + sigmoid, 4 users/block (unchanged).

#define B_ 4096
#define L_ 200
#define D_ 64

__global__ __launch_bounds__(64) void stats_kernel(
    const int* __restrict__ film_hist,
    const float* __restrict__ ratings,
    const int* __restrict__ lengths,
    const int* __restrict__ film_indices,
    const float* __restrict__ emb,
    float* __restrict__ x)
{
  __shared__ uint2 pair_s[L_];               // {h<<8, wgt bits}

  const int lane = threadIdx.x;
  const int b = blockIdx.x;
  const int n = lengths[b];                  // wave-uniform

  // film embedding (issue early; fully coalesced)
  const int fi = film_indices[b];
  const float fev = emb[(size_t)fi * D_ + lane];

  // ---- stage history+ratings into LDS (wave-local, no barrier) ----
  const int*   hp = film_hist + (size_t)b * L_;
  const float* rp = ratings  + (size_t)b * L_;
  int hv[4]; float rv[4]; float rsum = 0.f;
  #pragma unroll
  for (int j = 0; j < 4; ++j) {
    const int l = lane + 64*j;
    const bool v = l < n;
    hv[j] = v ? hp[l] : 0;
    rv[j] = v ? rp[l] : 0.f;
    rsum += v ? rv[j] : 0.f;
  }
  #pragma unroll
  for (int off = 32; off; off >>= 1) rsum += __shfl_xor(rsum, off);
  const float mr1 = 0.1f - rsum / (float)n;

  #pragma unroll
  for (int j = 0; j < 4; ++j) {
    const int l = lane + 64*j;
    if (l < n) {
      uint2 e; e.x = ((uint32_t)hv[j]) << 8;           // byte offset into emb
      e.y = __float_as_uint(rv[j] + mr1);
      pair_s[l] = e;
    }
  }

  // ---- gather + stats + bit-plane build: rows 0..n-1, 7 chunks of 32 ----
  float vmin = __builtin_inff(), vmax = -__builtin_inff(), vsum = 0.f;
  uint32_t PL[7][16];
  const char* eb = (const char*)emb;
  const uint32_t lane4 = (uint32_t)lane * 4u;

  #pragma unroll
  for (int c = 0; c < 7; ++c) {
    if (n > 32*c) {                          // wave-uniform guard
      uint32_t W[16];
      #pragma unroll
      for (int p = 0; p < 16; ++p) {
        const int i0 = 32*c + 2*p, i1 = i0 + 1;
        const int l0 = (i0 < n) ? i0 : (n-1);
        const int l1 = (i1 < n) ? i1 : (n-1);
        const uint2 e0 = pair_s[l0];
        const uint2 e1 = pair_s[l1];
        const float w0 = *(const float*)(eb + (e0.x + lane4)) * __uint_as_float(e0.y);
        const float w1 = *(const float*)(eb + (e1.x + lane4)) * __uint_as_float(e1.y);
        vmin = fminf(vmin, fminf(w0, w1));
        vmax = fmaxf(vmax, fmaxf(w0, w1));
        vsum += (i0 < n) ? w0 : 0.f;         // clamped dups masked out of sum
        vsum += (i1 < n) ? w1 : 0.f;
        const uint32_t u0 = __float_as_uint(w0);
        const uint32_t u1 = __float_as_uint(w1);
        const uint32_t k0 = u0 ^ (0x80000000u | (uint32_t)((int32_t)u0 >> 31));
        const uint32_t k1 = u1 ^ (0x80000000u | (uint32_t)((int32_t)u1 >> 31));
        W[p] = (k0 >> 16) | (k1 & 0xFFFF0000u);        // keys i0,i1 packed
      }
      // dual 16x16 bit-matrix transpose (verified): plane for key-bit bb is
      // W[15-bb]; key i sits at plane bit (15-(i>>1)) + 16*(i&1).
      #define XS(k, jj, m) { uint32_t tt = ((W[k] ^ (W[(k)|(jj)] >> (jj))) & (m)); \
                             W[k] ^= tt; W[(k)|(jj)] ^= (tt << (jj)); }
      XS(0,8,0x00FF00FFu) XS(1,8,0x00FF00FFu) XS(2,8,0x00FF00FFu) XS(3,8,0x00FF00FFu)
      XS(4,8,0x00FF00FFu) XS(5,8,0x00FF00FFu) XS(6,8,0x00FF00FFu) XS(7,8,0x00FF00FFu)
      XS(0,4,0x0F0F0F0Fu) XS(1,4,0x0F0F0F0Fu) XS(2,4,0x0F0F0F0Fu) XS(3,4,0x0F0F0F0Fu)
      XS(8,4,0x0F0F0F0Fu) XS(9,4,0x0F0F0F0Fu) XS(10,4,0x0F0F0F0Fu) XS(11,4,0x0F0F0F0Fu)
      XS(0,2,0x33333333u) XS(1,2,0x33333333u) XS(4,2,0x33333333u) XS(5,2,0x33333333u)
      XS(8,2,0x33333333u) XS(9,2,0x33333333u) XS(12,2,0x33333333u) XS(13,2,0x33333333u)
      XS(0,1,0x55555555u) XS(2,1,0x55555555u) XS(4,1,0x55555555u) XS(6,1,0x55555555u)
      XS(8,1,0x55555555u) XS(10,1,0x55555555u) XS(12,1,0x55555555u) XS(14,1,0x55555555u)
      #undef XS
      #pragma unroll
      for (int j = 0; j < 16; ++j) PL[c][j] = W[j];
    } else {
      #pragma unroll
      for (int j = 0; j < 16; ++j) PL[c][j] = 0u;
    }
  }

  // ---- alive masks (same verified formula, per chunk) ----
  uint32_t alive[7];
  #pragma unroll
  for (int c = 0; c < 7; ++c) {
    int v = n - 32*c; v = (v < 0) ? 0 : (v > 32 ? 32 : v);
    const int ce = (v + 1) >> 1, cf = v >> 1;
    uint32_t a = ((1u << ce) - 1u) << (16 - ce);
    if (cf) a |= ((1u << cf) - 1u) << (32 - cf);
    alive[c] = a;
  }

  // ---- bit-serial select of k-th smallest key: zero cross-lane ops ----
  int k = (n - 1) >> 1;
  int na = n;
  uint32_t prefix = 0;
  #pragma unroll
  for (int bb = 15; bb >= 0; --bb) {
    uint32_t t1[7];
    int cnt1 = 0;
    #pragma unroll
    for (int c = 0; c < 7; ++c) {
      t1[c] = alive[c] & PL[c][15 - bb];
      cnt1 += __popc(t1[c]);
    }
    const int cnt0 = na - cnt1;
    const bool zs = (k < cnt0);
    #pragma unroll
    for (int c = 0; c < 7; ++c)
      alive[c] = zs ? (alive[c] ^ t1[c]) : t1[c];
    na = zs ? cnt0 : cnt1;
    k  = zs ? k : (k - cnt0);
    prefix = zs ? prefix : (prefix | (1u << bb));
  }

  uint32_t key32 = (prefix << 16) | 0x8000u;           // bucket midpoint
  const float med = (prefix & 0x8000u) ? __uint_as_float(key32 ^ 0x80000000u)
                                       : __uint_as_float(~key32);
  const float mean = vsum / (float)n;

  // ---- L2-normalize (wave reduce of 4-term sumsq) and write x ----
  float ss = vmin*vmin + vmax*vmax + mean*mean + med*med;
  #pragma unroll
  for (int off = 32; off; off >>= 1) ss += __shfl_xor(ss, off);
  const float rn = 1.0f / sqrtf(ss);

  float* xb = x + (size_t)b * 320;
  xb[lane]        = vmin * rn;
  xb[64  + lane]  = vmax * rn;
  xb[128 + lane]  = mean * rn;
  xb[192 + lane]  = med  * rn;
  xb[256 + lane]  = fev;
}

#define U_ 4   // users per MLP block -> 1024 blocks

__global__ __launch_bounds__(256) void mlp_kernel(
    const float* __restrict__ x,
    const float* __restrict__ W1, const float* __restrict__ b1,
    const float* __restrict__ W2, const float* __restrict__ b2,
    const float* __restrict__ W3, const float* __restrict__ b3,
    float* __restrict__ out)
{
  __shared__ float xs[U_*320];
  __shared__ float h1s[U_*128];
  __shared__ float h2s[U_*64];
  const int t = threadIdx.x;
  const int u0 = blockIdx.x * U_;

  for (int i = t; i < U_*80; i += 256)
    ((float4*)xs)[i] = ((const float4*)(x + (size_t)u0*320))[i];
  __syncthreads();

  // h1 = relu(x @ W1 + b1): 4 users x 128 out; thread = (j, 2-user group)
  {
    const int j = t & 127, g = t >> 7;
    const int ub = g*2;
    float acc[2];
    const float bj = b1[j];
    acc[0] = bj; acc[1] = bj;
    for (int i = 0; i < 320; i += 4) {
      float w0 = W1[(i+0)*128 + j];
      float w1 = W1[(i+1)*128 + j];
      float w2 = W1[(i+2)*128 + j];
      float w3 = W1[(i+3)*128 + j];
      #pragma unroll
      for (int q = 0; q < 2; ++q) {
        float4 xv = *(const float4*)&xs[(ub+q)*320 + i];   // LDS broadcast in-wave
        acc[q] += xv.x*w0 + xv.y*w1 + xv.z*w2 + xv.w*w3;
      }
    }
    #pragma unroll
    for (int q = 0; q < 2; ++q) h1s[(ub+q)*128 + j] = fmaxf(acc[q], 0.f);
  }
  __syncthreads();

  // h2 = relu(h1 @ W2 + b2): 4 users x 64 out, 1 user per 64-thread group
  {
    const int j = t & 63, g = t >> 6;
    float acc = b2[j];
    for (int i = 0; i < 128; i += 4) {
      float w0 = W2[(i+0)*64 + j];
      float w1 = W2[(i+1)*64 + j];
      float w2 = W2[(i+2)*64 + j];
      float w3 = W2[(i+3)*64 + j];
      float4 hv = *(const float4*)&h1s[g*128 + i];
      acc += hv.x*w0 + hv.y*w1 + hv.z*w2 + hv.w*w3;
    }
    h2s[g*64 + j] = fmaxf(acc, 0.f);
  }
  __syncthreads();

  // out = sigmoid(h2 @ W3 + b3)
  if (t < U_*4) {
    const int u = t >> 2, sub = t & 3;
    float a = 0.f;
    #pragma unroll
    for (int i = 0; i < 16; ++i) a += h2s[u*64 + sub*16 + i] * W3[sub*16 + i];
    a += __shfl_xor(a, 1);
    a += __shfl_xor(a, 2);
    if (sub == 0) out[u0 + u] = 1.f / (1.f + __expf(-(a + b3[0])));
  }
}

extern "C" void kernel_launch(void* const* d_in, const int* in_sizes, int n_in,
                              void* d_out, int out_size, void* d_ws, size_t ws_size,
                              hipStream_t stream) {
  const int*   film_hist = (const int*)d_in[0];
  const float* ratings   = (const float*)d_in[1];
  const int*   lengths   = (const int*)d_in[2];
  const int*   film_idx  = (const int*)d_in[3];
  const float* emb       = (const float*)d_in[4];
  const float* W1 = (const float*)d_in[5];
  const float* b1 = (const float*)d_in[6];
  const float* W2 = (const float*)d_in[7];
  const float* b2 = (const float*)d_in[8];
  const float* W3 = (const float*)d_in[9];
  const float* b3 = (const float*)d_in[10];

  float* xbuf = (float*)d_ws;                 // B*320 f32 = 5.24 MB
  float* outp = (float*)d_out;

  stats_kernel<<<B_, 64, 0, stream>>>(film_hist, ratings, lengths, film_idx, emb, xbuf);
  mlp_kernel<<<B_/U_, 256, 0, stream>>>(xbuf, W1, b1, W2, b2, W3, b3, outp);
}